// Round 6
// baseline (98.775 us; speedup 1.0000x reference)
//
#include <hip/hip_runtime.h>

// A5ExactScan: s_{t+1} = mul[x_t, s_t] over T=2048 per row (B=16384), s0=0.
// Radix-2 chain, [s][p]-layout 6-bit-packed pair table in LDS:
//   bitpos = s*21600 + p*6  (row stride 2700 B). Word offset/shift depend only
//   on the token pair (off-chain). On-chain per pair:
//   v_mad_u32_u24 -> ds_read2_b32 -> v_alignbit_b32 -> v_and  (~170 cy).
//
// amdgpu_waves_per_eu(1,1) is REQUIRED: with extern-shared (compile-time size
// unknown) the backend otherwise targets 8 waves/EU and pressure-limits to
// ~20 VGPRs, demoting po/shv to scratch (scratch load on the chain: 255+
// cy/pair). Clamped: VGPR=132, 188 cy/pair measured.
//
// This round: sched_barrier(0)s REMOVED — they serialized PREP/moves/load
// issue AFTER the 8-hop chain region (~18 cy/pair of pure overhead). With one
// wave per SIMD only same-wave ILP can fill ds_read latency shadows, so the
// scheduler must be free to interleave off-chain work between hop issues.

#define T_LEN 2048
#define NTOK 60
#define NPAIR (NTOK * NTOK)             // 3600
#define ROW_WORDS 675                   // 3600*6/32
#define NWORDS (NTOK * ROW_WORDS)       // 40500
#define ALLOC_WORDS (NWORDS + 4)        // pad: last entry reads word 40500
#define TAB_BYTES (ALLOC_WORDS * 4)     // 162016 B
#define BROWS 64

// ---------------- kernel A: build packed [s][p] table in global scratch ----
__global__ void a5_build_kernel(const int* __restrict__ mul,
                                uint32_t* __restrict__ packed) {
  const int w = blockIdx.x * 256 + threadIdx.x;
  if (w >= ALLOC_WORDS) return;
  if (w >= NWORDS) { packed[w] = 0; return; }
  const uint32_t r = (uint32_t)w / ROW_WORDS;        // state s of this row
  const uint32_t woff = (uint32_t)w - r * ROW_WORDS; // word within row
  const uint32_t bit0 = woff * 32u;
  const uint32_t e0 = bit0 / 6u;
  const uint32_t sh0 = bit0 - e0 * 6u;
  uint64_t acc = 0;
#pragma unroll
  for (int k = 0; k < 7; ++k) {
    const uint32_t e = e0 + k;
    if (e < NPAIR) {
      const uint32_t x1 = e % 60u;
      const uint32_t x2 = e / 60u;
      const uint32_t v =
          (uint32_t)mul[x2 * 60u + (uint32_t)mul[x1 * 60u + r]];
      acc |= (uint64_t)v << (6 * k);
    }
  }
  packed[w] = (uint32_t)(acc >> sh0);
}

// ---------------- kernel B: per-row radix-2 chain ---------------------------
__global__ __launch_bounds__(BROWS)
__attribute__((amdgpu_waves_per_eu(1, 1)))
void a5_scan2_kernel(const int* __restrict__ ids,
                     const uint32_t* __restrict__ packed,
                     float* __restrict__ out) {
  extern __shared__ uint32_t tab[];  // ALLOC_WORDS u32
  const int lane = threadIdx.x;

  // Fill LDS table (162 KB; L2/L3-hot after first blocks).
  {
    const uint4* s4 = (const uint4*)packed;
    uint4* d4 = (uint4*)tab;
#pragma unroll 4
    for (int i = lane; i < ALLOC_WORDS / 4; i += BROWS) d4[i] = s4[i];
  }
  __syncthreads();

  const int row = blockIdx.x * BROWS + lane;
  const int4* rp = (const int4*)(ids + (size_t)row * T_LEN);
  const char* tb = (const char*)tab;

  uint32_t s = 0;  // state; s0 = identity id 0
  uint32_t po[8], shv[8];

#define PREP(J, X1, X2)                                           \
  do {                                                            \
    const uint32_t p6_ = (uint32_t)(X2)*360u + (uint32_t)(X1)*6u; \
    po[J] = (p6_ >> 5) << 2;                                      \
    shv[J] = p6_ & 31u;                                           \
  } while (0)

#define PSTEP(J)                                                  \
  do {                                                            \
    const uint32_t a_ = s * 2700u + po[J];                        \
    const uint32_t lo_ = *(const uint32_t*)(tb + a_);             \
    const uint32_t hi_ = *(const uint32_t*)(tb + a_ + 4);         \
    s = __builtin_amdgcn_alignbit(hi_, lo_, shv[J]) & 63u;        \
  } while (0)

  // Prologue: pairs for block 0 in po/shv; tokens for block 1 in n0..n3.
  int4 n0, n1, n2, n3;
  {
    int4 c0 = rp[0], c1 = rp[1], c2 = rp[2], c3 = rp[3];
    PREP(0, c0.x, c0.y); PREP(1, c0.z, c0.w);
    PREP(2, c1.x, c1.y); PREP(3, c1.z, c1.w);
    PREP(4, c2.x, c2.y); PREP(5, c2.z, c2.w);
    PREP(6, c3.x, c3.y); PREP(7, c3.z, c3.w);
    n0 = rp[4]; n1 = rp[5]; n2 = rp[6]; n3 = rp[7];
  }

  // Main loop: body b consumes po/shv (block b), PREPs block b+1 from n,
  // and issues loads for block b+2 (~2 iterations of vmcnt slack). The
  // scheduler is free to interleave PREP/moves/loads into the 8-hop chain's
  // ds_read latency shadows.
  for (int b = 0; b <= 125; ++b) {
    const int4* mp = rp + (size_t)(b + 2) * 4;
    int4 m0 = mp[0], m1 = mp[1], m2 = mp[2], m3 = mp[3];
    PSTEP(0); PSTEP(1); PSTEP(2); PSTEP(3);
    PSTEP(4); PSTEP(5); PSTEP(6); PSTEP(7);
    PREP(0, n0.x, n0.y); PREP(1, n0.z, n0.w);
    PREP(2, n1.x, n1.y); PREP(3, n1.z, n1.w);
    PREP(4, n2.x, n2.y); PREP(5, n2.z, n2.w);
    PREP(6, n3.x, n3.y); PREP(7, n3.z, n3.w);
    n0 = m0; n1 = m1; n2 = m2; n3 = m3;
  }
  // Epilogue: block 126 (in po/shv), then block 127 (PREP from n).
  PSTEP(0); PSTEP(1); PSTEP(2); PSTEP(3);
  PSTEP(4); PSTEP(5); PSTEP(6); PSTEP(7);
  PREP(0, n0.x, n0.y); PREP(1, n0.z, n0.w);
  PREP(2, n1.x, n1.y); PREP(3, n1.z, n1.w);
  PREP(4, n2.x, n2.y); PREP(5, n2.z, n2.w);
  PREP(6, n3.x, n3.y); PREP(7, n3.z, n3.w);
  PSTEP(0); PSTEP(1); PSTEP(2); PSTEP(3);
  PSTEP(4); PSTEP(5); PSTEP(6); PSTEP(7);
#undef PSTEP
#undef PREP

  // One-hot row write: 15 x float4 = 60 floats, fully overwrites output.
  float4* op = (float4*)(out + (size_t)row * NTOK);
#pragma unroll
  for (int j = 0; j < 15; ++j) {
    float4 v;
    v.x = ((uint32_t)(4 * j + 0) == s) ? 5.0f : 0.0f;
    v.y = ((uint32_t)(4 * j + 1) == s) ? 5.0f : 0.0f;
    v.z = ((uint32_t)(4 * j + 2) == s) ? 5.0f : 0.0f;
    v.w = ((uint32_t)(4 * j + 3) == s) ? 5.0f : 0.0f;
    op[j] = v;
  }
}

// ---------------- fallback: round-1 single-token chain ----------------------
__global__ __launch_bounds__(BROWS, 1) void a5_scan_kernel(
    const int* __restrict__ ids, const int* __restrict__ mul,
    float* __restrict__ out) {
  __shared__ uint32_t tab[NTOK * NTOK];
  const int lane = threadIdx.x;
  for (int i = lane; i < NTOK * NTOK; i += BROWS)
    tab[i] = ((uint32_t)mul[i]) << 2;
  __syncthreads();

  const int row = blockIdx.x * BROWS + lane;
  const int4* rp = (const int4*)(ids + (size_t)row * T_LEN);
  const char* tb = (const char*)tab;
  int4 c0 = rp[0], c1 = rp[1], c2 = rp[2], c3 = rp[3];
  uint32_t s4 = 0;
#define STEP(X)                                  \
  do {                                           \
    uint32_t base_ = (uint32_t)(X)*240u;         \
    s4 = *(const uint32_t*)(tb + base_ + s4);    \
  } while (0)
  for (int t = 0; t < T_LEN; t += 16) {
    int4 q0, q1, q2, q3;
    const bool more = (t + 16) < T_LEN;
    if (more) {
      const int4* np = rp + (t >> 2) + 4;
      q0 = np[0]; q1 = np[1]; q2 = np[2]; q3 = np[3];
    }
    STEP(c0.x); STEP(c0.y); STEP(c0.z); STEP(c0.w);
    STEP(c1.x); STEP(c1.y); STEP(c1.z); STEP(c1.w);
    STEP(c2.x); STEP(c2.y); STEP(c2.z); STEP(c2.w);
    STEP(c3.x); STEP(c3.y); STEP(c3.z); STEP(c3.w);
    if (more) { c0 = q0; c1 = q1; c2 = q2; c3 = q3; }
  }
#undef STEP
  const uint32_t s = s4 >> 2;
  float4* op = (float4*)(out + (size_t)row * NTOK);
#pragma unroll
  for (int j = 0; j < 15; ++j) {
    float4 v;
    v.x = ((uint32_t)(4 * j + 0) == s) ? 5.0f : 0.0f;
    v.y = ((uint32_t)(4 * j + 1) == s) ? 5.0f : 0.0f;
    v.z = ((uint32_t)(4 * j + 2) == s) ? 5.0f : 0.0f;
    v.w = ((uint32_t)(4 * j + 3) == s) ? 5.0f : 0.0f;
    op[j] = v;
  }
}

extern "C" void kernel_launch(void* const* d_in, const int* in_sizes, int n_in,
                              void* d_out, int out_size, void* d_ws,
                              size_t ws_size, hipStream_t stream) {
  const int* ids = (const int*)d_in[0];
  const int* mul = (const int*)d_in[1];
  float* out = (float*)d_out;
  const int B = in_sizes[0] / T_LEN;  // 16384
  const int grid = B / BROWS;         // 256 blocks

  if (ws_size >= (size_t)TAB_BYTES) {
    uint32_t* packed = (uint32_t*)d_ws;
    (void)hipFuncSetAttribute((const void*)a5_scan2_kernel,
                              hipFuncAttributeMaxDynamicSharedMemorySize,
                              TAB_BYTES);
    a5_build_kernel<<<(ALLOC_WORDS + 255) / 256, 256, 0, stream>>>(mul, packed);
    a5_scan2_kernel<<<grid, BROWS, TAB_BYTES, stream>>>(ids, packed, out);
  } else {
    a5_scan_kernel<<<grid, BROWS, 0, stream>>>(ids, mul, out);
  }
}

// Round 7
// 94.336 us; speedup vs baseline: 1.0471x; 1.0471x over previous
//
#include <hip/hip_runtime.h>

// A5ExactScan: s_{t+1} = mul[x_t, s_t] over T=2048 per row (B=16384), s0=0.
// Radix-2 chain, [s][p]-layout 6-bit-packed pair table in LDS:
//   bitpos = s*21600 + p*6  (row stride 2700 B). Word offset/shift depend only
//   on the token pair (off-chain). On-chain per pair:
//   v_mad_u32_u24 -> ds_read2_b32 -> v_alignbit_b32 -> v_and.
//
// Hard-won structure (rounds 2-6):
//  * amdgpu_waves_per_eu(1,1): REQUIRED. extern-shared size is unknown at
//    compile time -> backend targets 8 waves/EU -> ~20 VGPR budget -> po/sh
//    demoted to scratch -> scratch load ON the chain (~300 cy/pair).
//  * sched_barrier(0) immediately AFTER each load-issue group: REQUIRED.
//    Without it the scheduler sinks the loads toward their consumers
//    (live-range shrinking), exposing ~900 cy HBM latency per iter (round 6:
//    +13 us).
//  * This round: ping-pong unroll-by-2 (A/B token buffers, A/B po/sh sets).
//    Kills the 12 v_movs per iter and moves PREP INSIDE the chain region
//    (interleaved in source) so it can fill ds_read wait shadows instead of
//    running serially after the chain (round 5 cost: ~30 cy/pair).

#define T_LEN 2048
#define NTOK 60
#define NPAIR (NTOK * NTOK)             // 3600
#define ROW_WORDS 675                   // 3600*6/32
#define NWORDS (NTOK * ROW_WORDS)       // 40500
#define ALLOC_WORDS (NWORDS + 4)        // pad: last entry reads word 40500
#define TAB_BYTES (ALLOC_WORDS * 4)     // 162016 B
#define BROWS 64

// ---------------- kernel A: build packed [s][p] table in global scratch ----
__global__ void a5_build_kernel(const int* __restrict__ mul,
                                uint32_t* __restrict__ packed) {
  const int w = blockIdx.x * 256 + threadIdx.x;
  if (w >= ALLOC_WORDS) return;
  if (w >= NWORDS) { packed[w] = 0; return; }
  const uint32_t r = (uint32_t)w / ROW_WORDS;        // state s of this row
  const uint32_t woff = (uint32_t)w - r * ROW_WORDS; // word within row
  const uint32_t bit0 = woff * 32u;
  const uint32_t e0 = bit0 / 6u;
  const uint32_t sh0 = bit0 - e0 * 6u;
  uint64_t acc = 0;
#pragma unroll
  for (int k = 0; k < 7; ++k) {
    const uint32_t e = e0 + k;
    if (e < NPAIR) {
      const uint32_t x1 = e % 60u;
      const uint32_t x2 = e / 60u;
      const uint32_t v =
          (uint32_t)mul[x2 * 60u + (uint32_t)mul[x1 * 60u + r]];
      acc |= (uint64_t)v << (6 * k);
    }
  }
  packed[w] = (uint32_t)(acc >> sh0);
}

// ---------------- kernel B: per-row radix-2 chain ---------------------------
__global__ __launch_bounds__(BROWS)
__attribute__((amdgpu_waves_per_eu(1, 1)))
void a5_scan2_kernel(const int* __restrict__ ids,
                     const uint32_t* __restrict__ packed,
                     float* __restrict__ out) {
  extern __shared__ uint32_t tab[];  // ALLOC_WORDS u32
  const int lane = threadIdx.x;

  // Fill LDS table (162 KB; L2/L3-hot after first blocks).
  {
    const uint4* s4 = (const uint4*)packed;
    uint4* d4 = (uint4*)tab;
#pragma unroll 4
    for (int i = lane; i < ALLOC_WORDS / 4; i += BROWS) d4[i] = s4[i];
  }
  __syncthreads();

  const int row = blockIdx.x * BROWS + lane;
  const int4* rp = (const int4*)(ids + (size_t)row * T_LEN);
  const char* tb = (const char*)tab;

  uint32_t s = 0;  // state; s0 = identity id 0
  uint32_t poA[8], shA[8], poB[8], shB[8];
  int4 a0, a1, a2, a3;  // token buffer A (one 16-token block)
  int4 b0, b1, b2, b3;  // token buffer B

#define PREPA(J, X1, X2)                                          \
  do {                                                            \
    const uint32_t p6_ = (uint32_t)(X2)*360u + (uint32_t)(X1)*6u; \
    poA[J] = (p6_ >> 5) << 2;                                     \
    shA[J] = p6_ & 31u;                                           \
  } while (0)
#define PREPB(J, X1, X2)                                          \
  do {                                                            \
    const uint32_t p6_ = (uint32_t)(X2)*360u + (uint32_t)(X1)*6u; \
    poB[J] = (p6_ >> 5) << 2;                                     \
    shB[J] = p6_ & 31u;                                           \
  } while (0)

#define PSTEPA(J)                                                 \
  do {                                                            \
    const uint32_t a_ = s * 2700u + poA[J];                       \
    const uint32_t lo_ = *(const uint32_t*)(tb + a_);             \
    const uint32_t hi_ = *(const uint32_t*)(tb + a_ + 4);         \
    s = __builtin_amdgcn_alignbit(hi_, lo_, shA[J]) & 63u;        \
  } while (0)
#define PSTEPB(J)                                                 \
  do {                                                            \
    const uint32_t a_ = s * 2700u + poB[J];                       \
    const uint32_t lo_ = *(const uint32_t*)(tb + a_);             \
    const uint32_t hi_ = *(const uint32_t*)(tb + a_ + 4);         \
    s = __builtin_amdgcn_alignbit(hi_, lo_, shB[J]) & 63u;        \
  } while (0)

  // Prologue: poA = pairs(block 0); B = tokens(block 1).
  {
    int4 c0 = rp[0], c1 = rp[1], c2 = rp[2], c3 = rp[3];
    PREPA(0, c0.x, c0.y); PREPA(1, c0.z, c0.w);
    PREPA(2, c1.x, c1.y); PREPA(3, c1.z, c1.w);
    PREPA(4, c2.x, c2.y); PREPA(5, c2.z, c2.w);
    PREPA(6, c3.x, c3.y); PREPA(7, c3.z, c3.w);
    b0 = rp[4]; b1 = rp[5]; b2 = rp[6]; b3 = rp[7];
  }

  // Invariant entering iter k: poA = pairs(k), B = tokens(k+1).
  // 63 iterations chain blocks 0..125; epilogue chains 126, 127.
  for (int k = 0; k <= 124; k += 2) {
    {  // ---- half 1: chain block k, prep block k+1, load tokens(k+2) -> A
      const int4* mp = rp + (size_t)(k + 2) * 4;
      a0 = mp[0]; a1 = mp[1]; a2 = mp[2]; a3 = mp[3];
      __builtin_amdgcn_sched_barrier(0);  // pin load issue above the chain
      PSTEPA(0); PREPB(0, b0.x, b0.y);
      PSTEPA(1); PREPB(1, b0.z, b0.w);
      PSTEPA(2); PREPB(2, b1.x, b1.y);
      PSTEPA(3); PREPB(3, b1.z, b1.w);
      PSTEPA(4); PREPB(4, b2.x, b2.y);
      PSTEPA(5); PREPB(5, b2.z, b2.w);
      PSTEPA(6); PREPB(6, b3.x, b3.y);
      PSTEPA(7); PREPB(7, b3.z, b3.w);
    }
    {  // ---- half 2: chain block k+1, prep block k+2, load tokens(k+3) -> B
      const int4* mq = rp + (size_t)(k + 3) * 4;
      b0 = mq[0]; b1 = mq[1]; b2 = mq[2]; b3 = mq[3];
      __builtin_amdgcn_sched_barrier(0);
      PSTEPB(0); PREPA(0, a0.x, a0.y);
      PSTEPB(1); PREPA(1, a0.z, a0.w);
      PSTEPB(2); PREPA(2, a1.x, a1.y);
      PSTEPB(3); PREPA(3, a1.z, a1.w);
      PSTEPB(4); PREPA(4, a2.x, a2.y);
      PSTEPB(5); PREPA(5, a2.z, a2.w);
      PSTEPB(6); PREPA(6, a3.x, a3.y);
      PSTEPB(7); PREPA(7, a3.z, a3.w);
    }
  }
  // Epilogue: poA = pairs(126), B = tokens(127).
  PSTEPA(0); PREPB(0, b0.x, b0.y);
  PSTEPA(1); PREPB(1, b0.z, b0.w);
  PSTEPA(2); PREPB(2, b1.x, b1.y);
  PSTEPA(3); PREPB(3, b1.z, b1.w);
  PSTEPA(4); PREPB(4, b2.x, b2.y);
  PSTEPA(5); PREPB(5, b2.z, b2.w);
  PSTEPA(6); PREPB(6, b3.x, b3.y);
  PSTEPA(7); PREPB(7, b3.z, b3.w);
  PSTEPB(0); PSTEPB(1); PSTEPB(2); PSTEPB(3);
  PSTEPB(4); PSTEPB(5); PSTEPB(6); PSTEPB(7);
#undef PSTEPA
#undef PSTEPB
#undef PREPA
#undef PREPB

  // One-hot row write: 15 x float4 = 60 floats, fully overwrites output.
  float4* op = (float4*)(out + (size_t)row * NTOK);
#pragma unroll
  for (int j = 0; j < 15; ++j) {
    float4 v;
    v.x = ((uint32_t)(4 * j + 0) == s) ? 5.0f : 0.0f;
    v.y = ((uint32_t)(4 * j + 1) == s) ? 5.0f : 0.0f;
    v.z = ((uint32_t)(4 * j + 2) == s) ? 5.0f : 0.0f;
    v.w = ((uint32_t)(4 * j + 3) == s) ? 5.0f : 0.0f;
    op[j] = v;
  }
}

// ---------------- fallback: round-1 single-token chain ----------------------
__global__ __launch_bounds__(BROWS, 1) void a5_scan_kernel(
    const int* __restrict__ ids, const int* __restrict__ mul,
    float* __restrict__ out) {
  __shared__ uint32_t tab[NTOK * NTOK];
  const int lane = threadIdx.x;
  for (int i = lane; i < NTOK * NTOK; i += BROWS)
    tab[i] = ((uint32_t)mul[i]) << 2;
  __syncthreads();

  const int row = blockIdx.x * BROWS + lane;
  const int4* rp = (const int4*)(ids + (size_t)row * T_LEN);
  const char* tb = (const char*)tab;
  int4 c0 = rp[0], c1 = rp[1], c2 = rp[2], c3 = rp[3];
  uint32_t s4 = 0;
#define STEP(X)                                  \
  do {                                           \
    uint32_t base_ = (uint32_t)(X)*240u;         \
    s4 = *(const uint32_t*)(tb + base_ + s4);    \
  } while (0)
  for (int t = 0; t < T_LEN; t += 16) {
    int4 q0, q1, q2, q3;
    const bool more = (t + 16) < T_LEN;
    if (more) {
      const int4* np = rp + (t >> 2) + 4;
      q0 = np[0]; q1 = np[1]; q2 = np[2]; q3 = np[3];
    }
    STEP(c0.x); STEP(c0.y); STEP(c0.z); STEP(c0.w);
    STEP(c1.x); STEP(c1.y); STEP(c1.z); STEP(c1.w);
    STEP(c2.x); STEP(c2.y); STEP(c2.z); STEP(c2.w);
    STEP(c3.x); STEP(c3.y); STEP(c3.z); STEP(c3.w);
    if (more) { c0 = q0; c1 = q1; c2 = q2; c3 = q3; }
  }
#undef STEP
  const uint32_t s = s4 >> 2;
  float4* op = (float4*)(out + (size_t)row * NTOK);
#pragma unroll
  for (int j = 0; j < 15; ++j) {
    float4 v;
    v.x = ((uint32_t)(4 * j + 0) == s) ? 5.0f : 0.0f;
    v.y = ((uint32_t)(4 * j + 1) == s) ? 5.0f : 0.0f;
    v.z = ((uint32_t)(4 * j + 2) == s) ? 5.0f : 0.0f;
    v.w = ((uint32_t)(4 * j + 3) == s) ? 5.0f : 0.0f;
    op[j] = v;
  }
}

extern "C" void kernel_launch(void* const* d_in, const int* in_sizes, int n_in,
                              void* d_out, int out_size, void* d_ws,
                              size_t ws_size, hipStream_t stream) {
  const int* ids = (const int*)d_in[0];
  const int* mul = (const int*)d_in[1];
  float* out = (float*)d_out;
  const int B = in_sizes[0] / T_LEN;  // 16384
  const int grid = B / BROWS;         // 256 blocks

  if (ws_size >= (size_t)TAB_BYTES) {
    uint32_t* packed = (uint32_t*)d_ws;
    (void)hipFuncSetAttribute((const void*)a5_scan2_kernel,
                              hipFuncAttributeMaxDynamicSharedMemorySize,
                              TAB_BYTES);
    a5_build_kernel<<<(ALLOC_WORDS + 255) / 256, 256, 0, stream>>>(mul, packed);
    a5_scan2_kernel<<<grid, BROWS, TAB_BYTES, stream>>>(ids, packed, out);
  } else {
    a5_scan_kernel<<<grid, BROWS, 0, stream>>>(ids, mul, out);
  }
}